// Round 5
// baseline (118.968 us; speedup 1.0000x reference)
//
#include <hip/hip_runtime.h>

// MeanAggregator: out[b,:] = mean over UNIQUE cols c in row-segment b of embed[c,:]
// row_idx sorted ascending; duplicate (row,col) pairs count once (.set semantics).
//
// B = 4096 rows, U = 50000, D = 300, E = 131072 (avg deg 32, max ~60).
//
// Kernel 1 (build_rowptr_warm): CSR row pointers + SEQUENTIAL WARM of embed
//   into L3 via side-effecting global_load_lds (dummy LDS dest). The harness
//   re-poisons 268 MB of d_ws before every timed launch, flushing L3 — so all
//   60 MB of embed otherwise re-enters from HBM in RANDOM gather order (bad
//   DRAM efficiency, ~2.7 TB/s observed). Streaming it coalesced first makes
//   the HBM traffic sequential; the main kernel's gathers then hit L3.
// Kernel 2 (mean_agg): one wave per row, no barriers (round-4 structure):
//   shfl/ballot dedup + 4-deep unrolled branch-free float4 gather + direct store.

#define DFEAT  300
#define NCHUNK 75        // DFEAT / 4
#define CAP    128       // per-wave unique-col capacity (max realistic deg ~60)
#define WPB    4         // waves per 256-thread block (main kernel)

// Side-effecting 16B global->LDS load: never DCE'd, warms L2/L3, no VGPR use.
#define GLD_LDS16(gp, lp)                                                     \
    __builtin_amdgcn_global_load_lds(                                         \
        (const __attribute__((address_space(1))) unsigned int*)(gp),          \
        (__attribute__((address_space(3))) unsigned int*)(lp), 16, 0, 0)

__global__ __launch_bounds__(256) void build_rowptr_warm(
    const int* __restrict__ row_idx, int E, int B, int* __restrict__ row_ptr,
    const float4* __restrict__ embed4, int n_vec4)
{
    __shared__ float4 dummy[64];   // dump target for warm loads (1 KB, raced: fine)
    const int tid = threadIdx.x;
    const int e   = blockIdx.x * 256 + tid;

    // ---- CSR row pointers (same as round 3/4) ----
    if (e < E) {
        const int r     = row_idx[e];
        const int rprev = (e == 0) ? -1 : row_idx[e - 1];
        for (int x = rprev + 1; x <= r; ++x) row_ptr[x] = e;
        if (e == E - 1) {
            for (int x = r + 1; x <= B; ++x) row_ptr[x] = E;
        }
    }

    // ---- sequential warm of embed: grid-stride, perfectly coalesced ----
    const int stride = gridDim.x * 256;
    for (int i = e; i < n_vec4; i += stride) {
        GLD_LDS16(embed4 + i, &dummy[0]);
    }
}

__global__ __launch_bounds__(256) void mean_agg_kernel(
    const int* __restrict__ row_ptr,
    const int* __restrict__ col_idx,
    const float* __restrict__ embed,
    float* __restrict__ out,
    int B)
{
    const int lane = threadIdx.x & 63;
    const int w    = threadIdx.x >> 6;
    const int b    = blockIdx.x * WPB + w;
    if (b >= B) return;

    __shared__ int s_uniq[WPB][CAP];

    const int start = row_ptr[b];
    const int deg   = row_ptr[b + 1] - start;

    // ---- dedup + compact into s_uniq[w][0..cnt) (wave-local, no barriers) ----
    int cnt = 0;
    for (int base = 0; base < deg; base += 64) {
        const int  i     = base + lane;
        const bool valid = (i < deg);
        const int  c     = valid ? col_idx[start + i] : -1;

        bool dup = false;
        for (int q = 0; q < cnt; ++q) dup = dup || (s_uniq[w][q] == c);
        const int jmax = (deg - base - 1 < 63) ? (deg - base - 1) : 63;
        for (int j = 0; j < jmax; ++j) {
            const int cj = __shfl(c, j);
            dup = dup || ((j < lane) && (cj == c));
        }

        const unsigned long long m = __ballot(valid && !dup);
        const int rank = __popcll(m & ((1ull << lane) - 1ull));
        if (valid && !dup) {
            const int p = cnt + rank;
            if (p < CAP) s_uniq[w][p] = c;
        }
        cnt += (int)__popcll(m);
    }
    if (cnt > CAP) cnt = CAP;   // unreachable for this dataset; safety only

    // ---- gather: 4-deep unrolled, branch-free ----
    const bool hi = (lane < NCHUNK - 64);   // lanes 0..10 cover chunks 64..74
    float4 a0 = {0.f, 0.f, 0.f, 0.f};
    float4 a1 = {0.f, 0.f, 0.f, 0.f};

    int u = 0;
    for (; u + 4 <= cnt; u += 4) {
        const float4* __restrict__ p0 = (const float4*)(embed + (size_t)s_uniq[w][u    ] * DFEAT);
        const float4* __restrict__ p1 = (const float4*)(embed + (size_t)s_uniq[w][u + 1] * DFEAT);
        const float4* __restrict__ p2 = (const float4*)(embed + (size_t)s_uniq[w][u + 2] * DFEAT);
        const float4* __restrict__ p3 = (const float4*)(embed + (size_t)s_uniq[w][u + 3] * DFEAT);
        const float4 v0 = p0[lane];
        const float4 v1 = p1[lane];
        const float4 v2 = p2[lane];
        const float4 v3 = p3[lane];
        if (hi) {
            const float4 h0 = p0[lane + 64];
            const float4 h1 = p1[lane + 64];
            const float4 h2 = p2[lane + 64];
            const float4 h3 = p3[lane + 64];
            a1.x += h0.x + h1.x + h2.x + h3.x;
            a1.y += h0.y + h1.y + h2.y + h3.y;
            a1.z += h0.z + h1.z + h2.z + h3.z;
            a1.w += h0.w + h1.w + h2.w + h3.w;
        }
        a0.x += v0.x + v1.x + v2.x + v3.x;
        a0.y += v0.y + v1.y + v2.y + v3.y;
        a0.z += v0.z + v1.z + v2.z + v3.z;
        a0.w += v0.w + v1.w + v2.w + v3.w;
    }
    for (; u < cnt; ++u) {
        const float4* __restrict__ p0 = (const float4*)(embed + (size_t)s_uniq[w][u] * DFEAT);
        const float4 v0 = p0[lane];
        a0.x += v0.x; a0.y += v0.y; a0.z += v0.z; a0.w += v0.w;
        if (hi) {
            const float4 h0 = p0[lane + 64];
            a1.x += h0.x; a1.y += h0.y; a1.z += h0.z; a1.w += h0.w;
        }
    }

    // ---- scale + store ----
    const float s = (cnt > 0) ? (1.0f / (float)cnt) : 0.0f;
    float4* __restrict__ orow = (float4*)(out + (size_t)b * DFEAT);
    float4 r0; r0.x = a0.x * s; r0.y = a0.y * s; r0.z = a0.z * s; r0.w = a0.w * s;
    orow[lane] = r0;
    if (hi) {
        float4 r1; r1.x = a1.x * s; r1.y = a1.y * s; r1.z = a1.z * s; r1.w = a1.w * s;
        orow[lane + 64] = r1;
    }
}

extern "C" void kernel_launch(void* const* d_in, const int* in_sizes, int n_in,
                              void* d_out, int out_size, void* d_ws, size_t ws_size,
                              hipStream_t stream) {
    const int*   row_idx = (const int*)  d_in[0];
    const int*   col_idx = (const int*)  d_in[1];
    const float* embed   = (const float*)d_in[2];
    float*       out     = (float*)      d_out;

    const int E = in_sizes[0];            // 131072
    const int B = out_size / DFEAT;       // 4096
    const int U_D4 = in_sizes[2] / 4;     // embed float4 count = 3,750,000

    int* row_ptr = (int*)d_ws;            // (B+1) ints, rebuilt every call

    build_rowptr_warm<<<(E + 255) / 256, 256, 0, stream>>>(
        row_idx, E, B, row_ptr, (const float4*)embed, U_D4);
    mean_agg_kernel<<<(B + WPB - 1) / WPB, 256, 0, stream>>>(
        row_ptr, col_idx, embed, out, B);
}